// Round 14
// baseline (160.398 us; speedup 1.0000x reference)
//
#include <hip/hip_runtime.h>
#include <hip/hip_bf16.h>

// Problem constants
#define BATCH 32
#define LTOT 4096
#define CCH 64
#define NFFT 16
#define HOP 4
#define NF 9            // n_fft/2+1
#define T_FR 1025       // 1 + L/HOP
#define T_ROWS 1032     // padded rows in mag workspace (rows >= 1025 zeroed)
#define ICH 576         // C * NF
#define OCH 512
#define TY 1023         // conv output length
#define OUTW 128

typedef __attribute__((ext_vector_type(8))) _Float16 half8;
typedef __attribute__((ext_vector_type(4))) float floatx4;

// cos/sin(n*pi/8) for n = 0..15 — compile-time twiddles.
__device__ constexpr float C16[16] = {
    1.0f,  0.923879533f,  0.707106781f,  0.382683432f,  0.0f, -0.382683432f,
   -0.707106781f, -0.923879533f, -1.0f, -0.923879533f, -0.707106781f,
   -0.382683432f,  0.0f,  0.382683432f,  0.707106781f,  0.923879533f};
__device__ constexpr float S16[16] = {
    0.0f,  0.382683432f,  0.707106781f,  0.923879533f,  1.0f,  0.923879533f,
    0.707106781f,  0.382683432f,  0.0f, -0.382683432f, -0.707106781f,
   -0.923879533f, -1.0f, -0.923879533f, -0.707106781f, -0.382683432f};

#define BM 128
#define BN 192   // R14: staging-vs-occupancy midpoint (R7 BN=128/4blk 57.6us,
                 // R12 BN=256/2blk 55.3us) -> 3 blocks/CU, LDS 41.2 KB
#define NTW 6    // nt tiles per wave (BN/2/16)
#define BK 64

__device__ __forceinline__ void async_copy16(const _Float16* g, _Float16* l) {
  __builtin_amdgcn_global_load_lds(
      (const __attribute__((address_space(1))) unsigned int*)g,
      (__attribute__((address_space(3))) unsigned int*)l, 16, 0, 0);
}

// ---------------------------------------------------------------------------
// Kernel 1: STFT magnitude + weight repack (merged).
// x [B,L,C] fp32 -> m_ws [b][t][f*64+c] fp16 (f-major i-permutation, shared
// with the weight repack so the conv reduction is a pure GEMM over i).
// Folded real DFT (j<->16-j symmetry), constexpr twiddles.
// block = 256 = 64 c x 4 t; grid = (258 t-tiles, 32 b).  ~13 us = HBM floor.
// ---------------------------------------------------------------------------
__global__ __launch_bounds__(256) void stft_wrepack_kernel(
    const float* __restrict__ x, const float* __restrict__ weight,
    _Float16* __restrict__ m_ws, _Float16* __restrict__ wk) {
  const int b = blockIdx.y;
  const int t0 = blockIdx.x * 4;
  const int tid = threadIdx.x;

  // ---- weight repack slice (independent of stft work) ----
  const int gid = (b * 258 + blockIdx.x) * 256 + tid;
  if (gid < OCH * ICH) {
    int o = gid / ICH, i = gid - o * ICH;
    int c = i / 9, f = i - c * 9;
    const float* src = weight + (size_t)o * (ICH * 3) + i * 3;
    const size_t dst = (size_t)o * ICH + f * 64 + c;
#pragma unroll
    for (int k = 0; k < 3; ++k)
      wk[(size_t)k * OCH * ICH + dst] = (_Float16)src[k];
  }

  // ---- stft tile ----
  __shared__ float xs[28 * 64];   // frames for 4 t: 4*4+12 = 28 rows of x
  const int l0 = t0 * HOP - 8;
  const float* xb = x + (size_t)b * LTOT * CCH;
#pragma unroll
  for (int it = 0; it < 7; ++it) {
    int e = it * 256 + tid;
    int r = e >> 6, c = e & 63;
    int l = l0 + r;
    if (l < 0) l = -l;
    if (l >= LTOT) l = 2 * LTOT - 2 - l;
    xs[r * 64 + c] = xb[(size_t)l * CCH + c];
  }
  __syncthreads();

  const int c = tid & 63, tq = tid >> 6;
  const int t = t0 + tq;    // t <= 1031 < T_ROWS
  _Float16* o_ptr = m_ws + ((size_t)b * T_ROWS + t) * ICH + c;
  if (t >= T_FR) {
#pragma unroll
    for (int f = 0; f < NF; ++f) o_ptr[f * 64] = (_Float16)0.0f;
    return;
  }
  float wx[16];
#pragma unroll
  for (int j = 0; j < 16; ++j)
    wx[j] = xs[(tq * 4 + j) * 64 + c] * (0.5f * (1.0f - C16[j]));
  float s[8], d[8];
#pragma unroll
  for (int j = 1; j < 8; ++j) {
    s[j] = wx[j] + wx[16 - j];
    d[j] = wx[j] - wx[16 - j];
  }
#pragma unroll
  for (int f = 0; f < NF; ++f) {
    float re = wx[0] + ((f & 1) ? -wx[8] : wx[8]);
    float im = 0.0f;
#pragma unroll
    for (int j = 1; j < 8; ++j) {
      re += s[j] * C16[(f * j) & 15];
      im += d[j] * S16[(f * j) & 15];
    }
    o_ptr[f * 64] = (_Float16)sqrtf(re * re + im * im);
  }
}

// ---------------------------------------------------------------------------
// Kernel 2: conv-as-GEMM, 128(o) x 192(t) tile, 3 blocks/CU.
// global_load_lds width=16 + XOR swizzle; tap-shared B staging (rows
// t0..t0+193 staged once per i-block); A staged per tap.
//   y[b][t][o] = sum_k sum_i wk[k][o][i] * m[b][t+k][i]
// Epilogue loop order nt->r->mt: 4 mt-stores complete each contiguous 128 B
// segment adjacently -> L2 write-combine (R13: WRITE 60 -> 33 MB, verified).
// Last t-tile (t0=960) over-reads past m_ws into wk — finite fp16, and all
// affected outputs have t >= TY (bounds-checked) -> safe.
// NOTE (R5): no per-element atomics in epilogue (2.3x regression).
// NOTE (R9): no cooperative grid.sync fusion (3.7x regression).
// NOTE (R10): A must go through LDS via async DMA — direct L2 reads thrash
// the 4 MB XCD L2 (WRITE 45->112 MB, MfmaUtil 44->15%).
// grid = (6 t-tiles, 4 o-tiles, 32 b), block 256 (4 waves, 2(o) x 2(t-half)).
// ---------------------------------------------------------------------------
__global__ __launch_bounds__(256, 3) void conv_gemm_kernel(
    const _Float16* __restrict__ m_ws, const _Float16* __restrict__ wk,
    _Float16* __restrict__ y) {
  const int b = blockIdx.z;
  const int o0 = blockIdx.y * BM;
  const int t0 = blockIdx.x * BN;
  const int tid = threadIdx.x;
  const int wave = tid >> 6, lane = tid & 63;
  const int wm = wave >> 1, wn = wave & 1;     // 2x2 wave grid (o x t-half)

  __shared__ _Float16 as[BM * BK];        // 16 KB    (A: weights, tap-current)
  __shared__ _Float16 bs[(BN + 2) * BK];  // 24.25 KB (B: mag rows t0..t0+193)

  floatx4 acc[4][NTW];
#pragma unroll
  for (int mt = 0; mt < 4; ++mt)
#pragma unroll
    for (int nt = 0; nt < NTW; ++nt)
      acc[mt][nt] = (floatx4)0.0f;

  const _Float16* mb = m_ws + (size_t)b * T_ROWS * ICH;
  const int frow = lane & 15;
  const int quad = lane >> 4;
  const int l7 = lane & 7;
  const int srow = lane >> 3;
  const int ssrc_off = srow * ICH + (l7 ^ srow) * 8;

  for (int ib = 0; ib < 9; ++ib) {
    const int i0 = ib * 64;
    const _Float16* bg = mb + (size_t)t0 * ICH + i0;

    // stage B rows t0 .. t0+193 (24 full 8-row segments + one 2-row partial)
#pragma unroll
    for (int it = 0; it < 6; ++it) {
      const int seg = wave * 6 + it;
      async_copy16(bg + (size_t)(seg * 8) * ICH + ssrc_off, &bs[seg * 512]);
    }
    if (tid < 16)   // rows 192,193
      async_copy16(bg + (size_t)192 * ICH + ssrc_off, &bs[192 * 64]);

#pragma unroll
    for (int ksh = 0; ksh < 3; ++ksh) {
      // stage A (weights for tap ksh)
      const _Float16* ag = wk + ((size_t)ksh * OCH + o0) * ICH + i0;
#pragma unroll
      for (int it = 0; it < 4; ++it) {
        const int seg = wave * 4 + it;
        async_copy16(ag + (size_t)(seg * 8) * ICH + ssrc_off, &as[seg * 512]);
      }
      __syncthreads();   // drains vmcnt (B once per ib + A) + barrier

      const int rb7 = (frow + ksh) & 7;
#pragma unroll
      for (int kk2 = 0; kk2 < 2; ++kk2) {
        const int jj = kk2 * 4 + quad;
        const int coffA = ((jj ^ l7) << 3);
        const int coffB = ((jj ^ rb7) << 3);
        half8 af[4], bf[NTW];
#pragma unroll
        for (int mt = 0; mt < 4; ++mt)
          af[mt] = *(const half8*)(&as[(wm * 64 + mt * 16 + frow) * 64 + coffA]);
#pragma unroll
        for (int nt = 0; nt < NTW; ++nt)
          bf[nt] = *(const half8*)(
              &bs[(wn * 96 + nt * 16 + frow + ksh) * 64 + coffB]);
        // first operand = t-fragment => D row (quad*4+reg) = t, D col = o
#pragma unroll
        for (int mt = 0; mt < 4; ++mt)
#pragma unroll
          for (int nt = 0; nt < NTW; ++nt)
            acc[mt][nt] = __builtin_amdgcn_mfma_f32_16x16x32_f16(
                bf[nt], af[mt], acc[mt][nt], 0, 0, 0);
      }
      __syncthreads();
    }
  }

  // epilogue: y[b][t][o] fp16, t padded to 1024 rows of OCH halves.
  const int col = lane & 15;
  _Float16* yb = y + (((size_t)b << 10)) * OCH;
#pragma unroll
  for (int nt = 0; nt < NTW; ++nt) {
    const int tb = t0 + wn * 96 + nt * 16 + quad * 4;
#pragma unroll
    for (int r = 0; r < 4; ++r) {
      const int t = tb + r;
      if (t < TY) {
#pragma unroll
        for (int mt = 0; mt < 4; ++mt) {
          const int o = o0 + wm * 64 + mt * 16 + col;
          yb[(size_t)t * OCH + o] = (_Float16)acc[mt][nt][r];
        }
      }
    }
  }
}

// ---------------------------------------------------------------------------
// Kernel 3: adaptive avg pool (overlapping torch bins) + bias, half8 wide.
// out[b][w][o] = bias[o] + mean_{t in bin(w)} y[b][t][o]
// one (b, w, o-octet) per thread: 32*128*64 = 262144 = 1024 blocks x 256.
// ---------------------------------------------------------------------------
__global__ __launch_bounds__(256) void pool_kernel(const _Float16* __restrict__ y,
                                                   const float* __restrict__ bias,
                                                   float* __restrict__ out) {
  const int unit = blockIdx.x * 256 + threadIdx.x;
  const int b = unit >> 13;
  const int w = (unit >> 6) & 127;
  const int o = (unit & 63) * 8;
  const int start = (w * TY) >> 7;
  const int end = ((w + 1) * TY + 127) >> 7;
  const _Float16* yb = y + (((size_t)b << 10)) * OCH;
  float s[8];
#pragma unroll
  for (int i = 0; i < 8; ++i) s[i] = 0.0f;
  for (int t = start; t < end; ++t) {
    half8 v = *(const half8*)(yb + (size_t)t * OCH + o);
#pragma unroll
    for (int i = 0; i < 8; ++i) s[i] += (float)v[i];
  }
  const float inv = 1.0f / (float)(end - start);
  float* op = out + ((size_t)b * OUTW + w) * OCH + o;
  floatx4 r0, r1;
#pragma unroll
  for (int i = 0; i < 4; ++i) r0[i] = s[i] * inv + bias[o + i];
#pragma unroll
  for (int i = 0; i < 4; ++i) r1[i] = s[4 + i] * inv + bias[o + 4 + i];
  *(floatx4*)(op) = r0;
  *(floatx4*)(op + 4) = r1;
}

// ---------------------------------------------------------------------------
extern "C" void kernel_launch(void* const* d_in, const int* in_sizes, int n_in,
                              void* d_out, int out_size, void* d_ws, size_t ws_size,
                              hipStream_t stream) {
  const float* x = (const float*)d_in[0];       // [32, 4096, 64]
  const float* weight = (const float*)d_in[1];  // [512, 576, 3]
  const float* bias = (const float*)d_in[2];    // [512]
  float* out = (float*)d_out;                   // [32, 128, 512]

  char* ws = (char*)d_ws;
  const size_t m_bytes = (size_t)BATCH * T_ROWS * ICH * sizeof(_Float16);  // 38,043,648
  const size_t w_bytes = (size_t)3 * OCH * ICH * sizeof(_Float16);         // 1,769,472
  _Float16* m_ws = (_Float16*)ws;
  _Float16* wk = (_Float16*)(ws + m_bytes);
  _Float16* y = (_Float16*)(ws + m_bytes + w_bytes);  // [32][1024][512] fp16

  hipLaunchKernelGGL(stft_wrepack_kernel, dim3(258, BATCH), dim3(256), 0,
                     stream, x, weight, m_ws, wk);
  hipLaunchKernelGGL(conv_gemm_kernel, dim3(6, 4, BATCH), dim3(256), 0, stream,
                     m_ws, wk, y);
  hipLaunchKernelGGL(pool_kernel, dim3(OUTW * BATCH / 4), dim3(256), 0, stream,
                     y, bias, out);
}

// Round 15
// 146.807 us; speedup vs baseline: 1.0926x; 1.0926x over previous
//
#include <hip/hip_runtime.h>
#include <hip/hip_bf16.h>

// Problem constants
#define BATCH 32
#define LTOT 4096
#define CCH 64
#define NFFT 16
#define HOP 4
#define NF 9            // n_fft/2+1
#define T_FR 1025       // 1 + L/HOP
#define T_ROWS 1032     // padded rows in mag workspace (rows >= 1025 zeroed)
#define ICH 576         // C * NF
#define OCH 512
#define TY 1023         // conv output length
#define OUTW 128

typedef __attribute__((ext_vector_type(8))) _Float16 half8;
typedef __attribute__((ext_vector_type(4))) float floatx4;

// cos/sin(n*pi/8) for n = 0..15 — compile-time twiddles.
__device__ constexpr float C16[16] = {
    1.0f,  0.923879533f,  0.707106781f,  0.382683432f,  0.0f, -0.382683432f,
   -0.707106781f, -0.923879533f, -1.0f, -0.923879533f, -0.707106781f,
   -0.382683432f,  0.0f,  0.382683432f,  0.707106781f,  0.923879533f};
__device__ constexpr float S16[16] = {
    0.0f,  0.382683432f,  0.707106781f,  0.923879533f,  1.0f,  0.923879533f,
    0.707106781f,  0.382683432f,  0.0f, -0.382683432f, -0.707106781f,
   -0.923879533f, -1.0f, -0.923879533f, -0.707106781f, -0.382683432f};

#define BM 128
#define BN 256   // tile surface measured: BN=128 -> 57.6us, 192 -> 68.4us
                 // (FETCH 94MB: XCD scatter + over-read), 256 -> 55.3us. Keep 256.
#define BK 64

__device__ __forceinline__ void async_copy16(const _Float16* g, _Float16* l) {
  __builtin_amdgcn_global_load_lds(
      (const __attribute__((address_space(1))) unsigned int*)g,
      (__attribute__((address_space(3))) unsigned int*)l, 16, 0, 0);
}

// ---------------------------------------------------------------------------
// Kernel 1: STFT magnitude + weight repack (merged).
// x [B,L,C] fp32 -> m_ws [b][t][f*64+c] fp16 (f-major i-permutation, shared
// with the weight repack so the conv reduction is a pure GEMM over i).
// Folded real DFT (j<->16-j symmetry), constexpr twiddles.
// block = 256 = 64 c x 4 t; grid = (258 t-tiles, 32 b).  ~13 us = HBM floor.
// ---------------------------------------------------------------------------
__global__ __launch_bounds__(256) void stft_wrepack_kernel(
    const float* __restrict__ x, const float* __restrict__ weight,
    _Float16* __restrict__ m_ws, _Float16* __restrict__ wk) {
  const int b = blockIdx.y;
  const int t0 = blockIdx.x * 4;
  const int tid = threadIdx.x;

  // ---- weight repack slice (independent of stft work) ----
  const int gid = (b * 258 + blockIdx.x) * 256 + tid;
  if (gid < OCH * ICH) {
    int o = gid / ICH, i = gid - o * ICH;
    int c = i / 9, f = i - c * 9;
    const float* src = weight + (size_t)o * (ICH * 3) + i * 3;
    const size_t dst = (size_t)o * ICH + f * 64 + c;
#pragma unroll
    for (int k = 0; k < 3; ++k)
      wk[(size_t)k * OCH * ICH + dst] = (_Float16)src[k];
  }

  // ---- stft tile ----
  __shared__ float xs[28 * 64];   // frames for 4 t: 4*4+12 = 28 rows of x
  const int l0 = t0 * HOP - 8;
  const float* xb = x + (size_t)b * LTOT * CCH;
#pragma unroll
  for (int it = 0; it < 7; ++it) {
    int e = it * 256 + tid;
    int r = e >> 6, c = e & 63;
    int l = l0 + r;
    if (l < 0) l = -l;
    if (l >= LTOT) l = 2 * LTOT - 2 - l;
    xs[r * 64 + c] = xb[(size_t)l * CCH + c];
  }
  __syncthreads();

  const int c = tid & 63, tq = tid >> 6;
  const int t = t0 + tq;    // t <= 1031 < T_ROWS
  _Float16* o_ptr = m_ws + ((size_t)b * T_ROWS + t) * ICH + c;
  if (t >= T_FR) {
#pragma unroll
    for (int f = 0; f < NF; ++f) o_ptr[f * 64] = (_Float16)0.0f;
    return;
  }
  float wx[16];
#pragma unroll
  for (int j = 0; j < 16; ++j)
    wx[j] = xs[(tq * 4 + j) * 64 + c] * (0.5f * (1.0f - C16[j]));
  float s[8], d[8];
#pragma unroll
  for (int j = 1; j < 8; ++j) {
    s[j] = wx[j] + wx[16 - j];
    d[j] = wx[j] - wx[16 - j];
  }
#pragma unroll
  for (int f = 0; f < NF; ++f) {
    float re = wx[0] + ((f & 1) ? -wx[8] : wx[8]);
    float im = 0.0f;
#pragma unroll
    for (int j = 1; j < 8; ++j) {
      re += s[j] * C16[(f * j) & 15];
      im += d[j] * S16[(f * j) & 15];
    }
    o_ptr[f * 64] = (_Float16)sqrtf(re * re + im * im);
  }
}

// ---------------------------------------------------------------------------
// Kernel 2: conv-as-GEMM, 128(o) x 256(t) tile (R13 config, GEMM 55.3 us)
// + R15 XCD-aware work remap: the 4 o-tiles consuming one B-tile (same t,b)
// are assigned to linear block IDs {g%8 + 32*(g/8) + 8m}, all == g (mod 8),
// so under round-robin ID->XCD placement they share ONE XCD's L2 and B is
// fetched once per group (R14 showed placement geometry dominates FETCH:
// grid-x=6 scattered groups over 4 XCDs -> FETCH 94 MB, 68 us).
//   y[b][t][o] = sum_k sum_i wk[k][o][i] * m[b][t+k][i]
// Epilogue loop order nt->r->mt -> L2 write-combine (R13: WRITE 60->33 MB).
// NOTE (R5): no per-element atomics in epilogue (2.3x regression).
// NOTE (R9): no cooperative grid.sync fusion (3.7x regression).
// NOTE (R10): A must go through LDS via async DMA — direct L2 reads thrash
// the 4 MB XCD L2 (WRITE 45->112 MB, MfmaUtil 44->15%).
// grid = 512 linear blocks, block 256 (4 waves, 2(o) x 2(t-half)).
// ---------------------------------------------------------------------------
__global__ __launch_bounds__(256, 2) void conv_gemm_kernel(
    const _Float16* __restrict__ m_ws, const _Float16* __restrict__ wk,
    _Float16* __restrict__ y) {
  // XCD-aware remap of linear ID -> (t-tile, o-tile, batch)
  const int lid = blockIdx.x;            // 0..511
  const int xcd = lid & 7;
  const int rest = lid >> 3;             // 0..63
  const int m = rest & 3;                // o-tile member 0..3
  const int gg = rest >> 2;              // 0..15
  const int g = xcd + 8 * gg;            // B-tile group 0..127 = (t,b)
  const int b = g >> 2;
  const int o0 = m * BM;
  const int t0 = (g & 3) * BN;

  const int tid = threadIdx.x;
  const int wave = tid >> 6, lane = tid & 63;
  const int wm = wave >> 1, wn = wave & 1;     // 2x2 wave grid (o x t-half)

  __shared__ _Float16 as[BM * BK];        // 16 KB    (A: weights, tap-current)
  __shared__ _Float16 bs[(BN + 2) * BK];  // 32.25 KB (B: mag rows t0..t0+257)

  floatx4 acc[4][8];
#pragma unroll
  for (int mt = 0; mt < 4; ++mt)
#pragma unroll
    for (int nt = 0; nt < 8; ++nt)
      acc[mt][nt] = (floatx4)0.0f;

  const _Float16* mb = m_ws + (size_t)b * T_ROWS * ICH;
  const int frow = lane & 15;
  const int quad = lane >> 4;
  const int l7 = lane & 7;
  const int srow = lane >> 3;
  const int ssrc_off = srow * ICH + (l7 ^ srow) * 8;

  for (int ib = 0; ib < 9; ++ib) {
    const int i0 = ib * 64;
    const _Float16* bg = mb + (size_t)t0 * ICH + i0;

    // stage B rows t0 .. t0+257 (32 full 8-row segments + one 2-row partial)
#pragma unroll
    for (int it = 0; it < 8; ++it) {
      const int seg = wave * 8 + it;
      async_copy16(bg + (size_t)(seg * 8) * ICH + ssrc_off, &bs[seg * 512]);
    }
    if (tid < 16)   // rows 256,257 (t0 max 768 -> row 1025 < T_ROWS)
      async_copy16(bg + (size_t)256 * ICH + ssrc_off, &bs[256 * 64]);

#pragma unroll
    for (int ksh = 0; ksh < 3; ++ksh) {
      // stage A (weights for tap ksh)
      const _Float16* ag = wk + ((size_t)ksh * OCH + o0) * ICH + i0;
#pragma unroll
      for (int it = 0; it < 4; ++it) {
        const int seg = wave * 4 + it;
        async_copy16(ag + (size_t)(seg * 8) * ICH + ssrc_off, &as[seg * 512]);
      }
      __syncthreads();   // drains vmcnt (B once per ib + A) + barrier

      const int rb7 = (frow + ksh) & 7;
#pragma unroll
      for (int kk2 = 0; kk2 < 2; ++kk2) {
        const int jj = kk2 * 4 + quad;
        const int coffA = ((jj ^ l7) << 3);
        const int coffB = ((jj ^ rb7) << 3);
        half8 af[4], bf[8];
#pragma unroll
        for (int mt = 0; mt < 4; ++mt)
          af[mt] = *(const half8*)(&as[(wm * 64 + mt * 16 + frow) * 64 + coffA]);
#pragma unroll
        for (int nt = 0; nt < 8; ++nt)
          bf[nt] = *(const half8*)(
              &bs[(wn * 128 + nt * 16 + frow + ksh) * 64 + coffB]);
        // first operand = t-fragment => D row (quad*4+reg) = t, D col = o
#pragma unroll
        for (int mt = 0; mt < 4; ++mt)
#pragma unroll
          for (int nt = 0; nt < 8; ++nt)
            acc[mt][nt] = __builtin_amdgcn_mfma_f32_16x16x32_f16(
                bf[nt], af[mt], acc[mt][nt], 0, 0, 0);
      }
      __syncthreads();
    }
  }

  // epilogue: y[b][t][o] fp16, t padded to 1024 rows of OCH halves.
  // Loop order nt->r->mt: 4 mt-stores complete each contiguous 128 B segment
  // adjacently in program order -> L2 write-combine (R13 verified).
  const int col = lane & 15;
  _Float16* yb = y + (((size_t)b << 10)) * OCH;
#pragma unroll
  for (int nt = 0; nt < 8; ++nt) {
    const int tb = t0 + wn * 128 + nt * 16 + quad * 4;
#pragma unroll
    for (int r = 0; r < 4; ++r) {
      const int t = tb + r;
      if (t < TY) {
#pragma unroll
        for (int mt = 0; mt < 4; ++mt) {
          const int o = o0 + wm * 64 + mt * 16 + col;
          yb[(size_t)t * OCH + o] = (_Float16)acc[mt][nt][r];
        }
      }
    }
  }
}

// ---------------------------------------------------------------------------
// Kernel 3: adaptive avg pool (overlapping torch bins) + bias, half8 wide.
// out[b][w][o] = bias[o] + mean_{t in bin(w)} y[b][t][o]
// one (b, w, o-octet) per thread: 32*128*64 = 262144 = 1024 blocks x 256.
// ---------------------------------------------------------------------------
__global__ __launch_bounds__(256) void pool_kernel(const _Float16* __restrict__ y,
                                                   const float* __restrict__ bias,
                                                   float* __restrict__ out) {
  const int unit = blockIdx.x * 256 + threadIdx.x;
  const int b = unit >> 13;
  const int w = (unit >> 6) & 127;
  const int o = (unit & 63) * 8;
  const int start = (w * TY) >> 7;
  const int end = ((w + 1) * TY + 127) >> 7;
  const _Float16* yb = y + (((size_t)b << 10)) * OCH;
  float s[8];
#pragma unroll
  for (int i = 0; i < 8; ++i) s[i] = 0.0f;
  for (int t = start; t < end; ++t) {
    half8 v = *(const half8*)(yb + (size_t)t * OCH + o);
#pragma unroll
    for (int i = 0; i < 8; ++i) s[i] += (float)v[i];
  }
  const float inv = 1.0f / (float)(end - start);
  float* op = out + ((size_t)b * OUTW + w) * OCH + o;
  floatx4 r0, r1;
#pragma unroll
  for (int i = 0; i < 4; ++i) r0[i] = s[i] * inv + bias[o + i];
#pragma unroll
  for (int i = 0; i < 4; ++i) r1[i] = s[4 + i] * inv + bias[o + 4 + i];
  *(floatx4*)(op) = r0;
  *(floatx4*)(op + 4) = r1;
}

// ---------------------------------------------------------------------------
extern "C" void kernel_launch(void* const* d_in, const int* in_sizes, int n_in,
                              void* d_out, int out_size, void* d_ws, size_t ws_size,
                              hipStream_t stream) {
  const float* x = (const float*)d_in[0];       // [32, 4096, 64]
  const float* weight = (const float*)d_in[1];  // [512, 576, 3]
  const float* bias = (const float*)d_in[2];    // [512]
  float* out = (float*)d_out;                   // [32, 128, 512]

  char* ws = (char*)d_ws;
  const size_t m_bytes = (size_t)BATCH * T_ROWS * ICH * sizeof(_Float16);  // 38,043,648
  const size_t w_bytes = (size_t)3 * OCH * ICH * sizeof(_Float16);         // 1,769,472
  _Float16* m_ws = (_Float16*)ws;
  _Float16* wk = (_Float16*)(ws + m_bytes);
  _Float16* y = (_Float16*)(ws + m_bytes + w_bytes);  // [32][1024][512] fp16

  hipLaunchKernelGGL(stft_wrepack_kernel, dim3(258, BATCH), dim3(256), 0,
                     stream, x, weight, m_ws, wk);
  hipLaunchKernelGGL(conv_gemm_kernel, dim3(512), dim3(256), 0, stream,
                     m_ws, wk, y);
  hipLaunchKernelGGL(pool_kernel, dim3(OUTW * BATCH / 4), dim3(256), 0, stream,
                     y, bias, out);
}